// Round 1
// baseline (747.999 us; speedup 1.0000x reference)
//
#include <hip/hip_runtime.h>
#include <hip/hip_bf16.h>

#define GN 10000
#define GE 160000
#define GH 4
#define GD 128
#define GHD 512
#define GB 64
#define GC 2
#define GFF 768
#define SLOPE 0.2f

__device__ __forceinline__ float leaky(float x) { return x >= 0.0f ? x : SLOPE * x; }

// ---------------- GEMM: [rows,128] x [128,512] -> [rows,512], rows % 16 == 0
__global__ __launch_bounds__(256) void gemm_128x512(const float* __restrict__ X,
                                                    const float* __restrict__ W,
                                                    float* __restrict__ Y) {
    __shared__ float xs[16 * 128];
    const int row0 = blockIdx.x * 16;
    const int t = threadIdx.x;
    const float4* X4 = (const float4*)(X + (size_t)row0 * 128);
    float4* xs4v = (float4*)xs;
#pragma unroll
    for (int i = 0; i < 2; ++i) xs4v[i * 256 + t] = X4[i * 256 + t];
    __syncthreads();
    const int c0 = t, c1 = t + 256;
    float acc0[16], acc1[16];
#pragma unroll
    for (int r = 0; r < 16; ++r) { acc0[r] = 0.f; acc1[r] = 0.f; }
    const float4* xs4 = (const float4*)xs;
    for (int f4 = 0; f4 < 32; ++f4) {
        float w0q[4], w1q[4];
#pragma unroll
        for (int q = 0; q < 4; ++q) {
            w0q[q] = W[(f4 * 4 + q) * 512 + c0];
            w1q[q] = W[(f4 * 4 + q) * 512 + c1];
        }
#pragma unroll
        for (int r = 0; r < 16; ++r) {
            float4 xv = xs4[r * 32 + f4];
            acc0[r] += xv.x * w0q[0] + xv.y * w0q[1] + xv.z * w0q[2] + xv.w * w0q[3];
            acc1[r] += xv.x * w1q[0] + xv.y * w1q[1] + xv.z * w1q[2] + xv.w * w1q[3];
        }
    }
#pragma unroll
    for (int r = 0; r < 16; ++r) {
        Y[(size_t)(row0 + r) * 512 + c0] = acc0[r];
        Y[(size_t)(row0 + r) * 512 + c1] = acc1[r];
    }
}

// ---------------- per-node attention logits: el[n,h] = <hpre[n,h,:], al[h,:]>, er likewise
__global__ __launch_bounds__(256) void node_logits(const float* __restrict__ hpre,
                                                   const float* __restrict__ al,
                                                   const float* __restrict__ ar,
                                                   float* __restrict__ el,
                                                   float* __restrict__ er) {
    const int wid = threadIdx.x >> 6;
    const int lane = threadIdx.x & 63;
    const int n = blockIdx.x * 4 + wid;
    if (n >= GN) return;
    const float* hp = hpre + (size_t)n * 512;
#pragma unroll
    for (int h = 0; h < 4; ++h) {
        float h0 = hp[h * 128 + lane], h1 = hp[h * 128 + 64 + lane];
        float a = h0 * al[h * 128 + lane] + h1 * al[h * 128 + 64 + lane];
        float b = h0 * ar[h * 128 + lane] + h1 * ar[h * 128 + 64 + lane];
#pragma unroll
        for (int off = 32; off; off >>= 1) {
            a += __shfl_xor(a, off);
            b += __shfl_xor(b, off);
        }
        if (lane == 0) { el[n * 4 + h] = a; er[n * 4 + h] = b; }
    }
}

// ---------------- per-edge: ex = exp(leaky(el[src]+er[dst])); denom[dst] += ex
__global__ __launch_bounds__(256) void edge_exp(const int* __restrict__ src,
                                                const int* __restrict__ dst,
                                                const float* __restrict__ el,
                                                const float* __restrict__ er,
                                                float* __restrict__ ex,
                                                float* __restrict__ denom) {
    const int e = blockIdx.x * blockDim.x + threadIdx.x;
    if (e >= GE) return;
    const int s = src[e], d = dst[e];
#pragma unroll
    for (int h = 0; h < 4; ++h) {
        float v = leaky(el[s * 4 + h] + er[d * 4 + h]);
        float z = __expf(v);
        ex[e * 4 + h] = z;
        atomicAdd(&denom[d * 4 + h], z);
    }
}

// ---------------- per-edge aggregation: out[dst,h,:] += a[e,h]*hpre[src,h,:] ; optional aw write
__global__ __launch_bounds__(256) void edge_aggregate(const int* __restrict__ src,
                                                      const int* __restrict__ dst,
                                                      const float* __restrict__ hpre,
                                                      const float* __restrict__ ex,
                                                      const float* __restrict__ denom,
                                                      float* __restrict__ out,
                                                      float* __restrict__ aw_out) {
    const int w = (blockIdx.x * blockDim.x + threadIdx.x) >> 6;  // one wave per edge
    const int lane = threadIdx.x & 63;
    if (w >= GE) return;
    const int s = src[w], d = dst[w];
    const float4 exv = ((const float4*)ex)[w];
    const float4 dnv = ((const float4*)denom)[d];
    const float a0 = exv.x / fmaxf(dnv.x, 1e-9f);
    const float a1 = exv.y / fmaxf(dnv.y, 1e-9f);
    const float a2 = exv.z / fmaxf(dnv.z, 1e-9f);
    const float a3 = exv.w / fmaxf(dnv.w, 1e-9f);
    if (aw_out != nullptr && lane == 0) {
        aw_out[w * 4 + 0] = a0;
        aw_out[w * 4 + 1] = a1;
        aw_out[w * 4 + 2] = a2;
        aw_out[w * 4 + 3] = a3;
    }
    const float* hs = hpre + (size_t)s * 512;
    float* od = out + (size_t)d * 512;
    atomicAdd(&od[0 * 128 + lane],      a0 * hs[0 * 128 + lane]);
    atomicAdd(&od[0 * 128 + 64 + lane], a0 * hs[0 * 128 + 64 + lane]);
    atomicAdd(&od[1 * 128 + lane],      a1 * hs[1 * 128 + lane]);
    atomicAdd(&od[1 * 128 + 64 + lane], a1 * hs[1 * 128 + 64 + lane]);
    atomicAdd(&od[2 * 128 + lane],      a2 * hs[2 * 128 + lane]);
    atomicAdd(&od[2 * 128 + 64 + lane], a2 * hs[2 * 128 + 64 + lane]);
    atomicAdd(&od[3 * 128 + lane],      a3 * hs[3 * 128 + lane]);
    atomicAdd(&od[3 * 128 + 64 + lane], a3 * hs[3 * 128 + 64 + lane]);
}

// ---------------- layer-1 post: mean over heads (+bias), LayerNorm(128), leaky -> h1[N,128]
__global__ __launch_bounds__(256) void post1(const float* __restrict__ agg,
                                             const float* __restrict__ b1,
                                             const float* __restrict__ ln_g,
                                             const float* __restrict__ ln_b,
                                             float* __restrict__ h1) {
    const int wid = threadIdx.x >> 6;
    const int lane = threadIdx.x & 63;
    const int n = blockIdx.x * 4 + wid;
    if (n >= GN) return;
    const float* ag = agg + (size_t)n * 512;
    float v0 = 0.f, v1 = 0.f;
#pragma unroll
    for (int h = 0; h < 4; ++h) {
        v0 += ag[h * 128 + lane] + b1[h * 128 + lane];
        v1 += ag[h * 128 + 64 + lane] + b1[h * 128 + 64 + lane];
    }
    v0 *= 0.25f; v1 *= 0.25f;
    float s = v0 + v1;
#pragma unroll
    for (int off = 32; off; off >>= 1) s += __shfl_xor(s, off);
    const float mean = s * (1.0f / 128.0f);
    const float d0 = v0 - mean, d1 = v1 - mean;
    float q = d0 * d0 + d1 * d1;
#pragma unroll
    for (int off = 32; off; off >>= 1) q += __shfl_xor(q, off);
    const float inv = rsqrtf(q * (1.0f / 128.0f) + 1e-5f);
    h1[(size_t)n * 128 + lane]      = leaky(d0 * inv * ln_g[lane] + ln_b[lane]);
    h1[(size_t)n * 128 + 64 + lane] = leaky(d1 * inv * ln_g[64 + lane] + ln_b[64 + lane]);
}

// ---------------- layer-2 post + per-graph max pool (monotone-uint atomicMax)
__global__ __launch_bounds__(256) void post2_pool(const float* __restrict__ agg,
                                                  const float* __restrict__ b2,
                                                  const int* __restrict__ gid,
                                                  unsigned* __restrict__ pooled) {
    const int total = GN * 512;
    for (int idx = blockIdx.x * blockDim.x + threadIdx.x; idx < total;
         idx += gridDim.x * blockDim.x) {
        const int n = idx >> 9, c = idx & 511;
        float v = leaky(agg[idx] + b2[c]);
        unsigned bits = __float_as_uint(v);
        unsigned key = (bits & 0x80000000u) ? ~bits : (bits | 0x80000000u);
        atomicMax(&pooled[(size_t)gid[n] * 512 + c], key);
    }
}

__device__ __forceinline__ float blk_sum(float v, float* red) {
#pragma unroll
    for (int off = 32; off; off >>= 1) v += __shfl_xor(v, off);
    const int wid = threadIdx.x >> 6, lane = threadIdx.x & 63;
    __syncthreads();
    if (lane == 0) red[wid] = v;
    __syncthreads();
    return red[0] + red[1] + red[2] + red[3];
}

// ---------------- head MLP: one block per graph
__global__ __launch_bounds__(256) void head_mlp(const unsigned* __restrict__ pooled,
                                                const float* __restrict__ Wa, const float* __restrict__ ba,
                                                const float* __restrict__ Wb, const float* __restrict__ bb,
                                                const float* __restrict__ g2, const float* __restrict__ bt2,
                                                const float* __restrict__ Wc, const float* __restrict__ bc,
                                                float* __restrict__ probs) {
    __shared__ float p[512];
    __shared__ float z1[128];
    __shared__ float z2[768];
    __shared__ float red[4];
    const int g = blockIdx.x, t = threadIdx.x;
    for (int i = t; i < 512; i += 256) {
        unsigned key = pooled[(size_t)g * 512 + i];
        unsigned bits = (key & 0x80000000u) ? (key ^ 0x80000000u) : ~key;
        p[i] = __uint_as_float(bits);
    }
    __syncthreads();
    for (int j = t; j < 128; j += 256) {
        float acc = ba[j];
        for (int c = 0; c < 512; ++c) acc += p[c] * Wa[c * 128 + j];
        z1[j] = acc;
    }
    __syncthreads();
    for (int k = t; k < 768; k += 256) {
        float acc = bb[k];
        for (int j = 0; j < 128; ++j) acc += z1[j] * Wb[j * 768 + k];
        z2[k] = acc;
    }
    __syncthreads();
    float s = 0.f;
    for (int k = t; k < 768; k += 256) s += z2[k];
    const float mean = blk_sum(s, red) * (1.0f / 768.0f);
    float q = 0.f;
    for (int k = t; k < 768; k += 256) { float d = z2[k] - mean; q += d * d; }
    const float inv = rsqrtf(blk_sum(q, red) * (1.0f / 768.0f) + 1e-5f);
    __syncthreads();
    for (int k = t; k < 768; k += 256)
        z2[k] = leaky((z2[k] - mean) * inv * g2[k] + bt2[k]);
    __syncthreads();
    float a0 = 0.f, a1 = 0.f;
    for (int k = t; k < 768; k += 256) { a0 += z2[k] * Wc[k * 2]; a1 += z2[k] * Wc[k * 2 + 1]; }
    a0 = blk_sum(a0, red);
    a1 = blk_sum(a1, red);
    if (t == 0) {
        a0 += bc[0]; a1 += bc[1];
        const float m = fmaxf(a0, a1);
        const float e0 = __expf(a0 - m), e1 = __expf(a1 - m);
        const float den = e0 + e1;
        probs[g * 2 + 0] = e0 / den;
        probs[g * 2 + 1] = e1 / den;
    }
}

extern "C" void kernel_launch(void* const* d_in, const int* in_sizes, int n_in,
                              void* d_out, int out_size, void* d_ws, size_t ws_size,
                              hipStream_t stream) {
    const float* x   = (const float*)d_in[0];
    const int* src   = (const int*)d_in[1];
    const int* dst   = (const int*)d_in[2];
    const int* gid   = (const int*)d_in[3];
    const float* W1  = (const float*)d_in[4];
    const float* al1 = (const float*)d_in[5];
    const float* ar1 = (const float*)d_in[6];
    const float* b1  = (const float*)d_in[7];
    const float* lng = (const float*)d_in[8];
    const float* lnb = (const float*)d_in[9];
    const float* W2  = (const float*)d_in[10];
    const float* al2 = (const float*)d_in[11];
    const float* ar2 = (const float*)d_in[12];
    const float* b2  = (const float*)d_in[13];
    const float* Wa  = (const float*)d_in[14];
    const float* ba  = (const float*)d_in[15];
    const float* Wb  = (const float*)d_in[16];
    const float* bb  = (const float*)d_in[17];
    const float* g2  = (const float*)d_in[18];
    const float* bt2 = (const float*)d_in[19];
    const float* Wc  = (const float*)d_in[20];
    const float* bc  = (const float*)d_in[21];

    float* ws = (float*)d_ws;
    float* hpre  = ws;                                 // N*512
    float* agg   = hpre + (size_t)GN * 512;            // N*512
    float* h1    = agg + (size_t)GN * 512;             // N*128
    float* el    = h1 + (size_t)GN * 128;              // N*4
    float* er    = el + GN * 4;                        // N*4
    float* denom = er + GN * 4;                        // N*4
    float* ex1   = denom + GN * 4;                     // E*4
    unsigned* pooled = (unsigned*)(ex1 + (size_t)GE * 4);  // B*512

    float* probs = (float*)d_out;
    float* aw = probs + GB * GC;  // E*4 floats

    // ---- layer 1
    gemm_128x512<<<GN / 16, 256, 0, stream>>>(x, W1, hpre);
    node_logits<<<(GN + 3) / 4, 256, 0, stream>>>(hpre, al1, ar1, el, er);
    hipMemsetAsync(denom, 0, GN * 4 * sizeof(float), stream);
    edge_exp<<<(GE + 255) / 256, 256, 0, stream>>>(src, dst, el, er, ex1, denom);
    hipMemsetAsync(agg, 0, (size_t)GN * 512 * sizeof(float), stream);
    edge_aggregate<<<(GE + 3) / 4, 256, 0, stream>>>(src, dst, hpre, ex1, denom, agg, nullptr);
    post1<<<(GN + 3) / 4, 256, 0, stream>>>(agg, b1, lng, lnb, h1);

    // ---- layer 2
    gemm_128x512<<<GN / 16, 256, 0, stream>>>(h1, W2, hpre);
    node_logits<<<(GN + 3) / 4, 256, 0, stream>>>(hpre, al2, ar2, el, er);
    hipMemsetAsync(denom, 0, GN * 4 * sizeof(float), stream);
    edge_exp<<<(GE + 255) / 256, 256, 0, stream>>>(src, dst, el, er, aw, denom);
    hipMemsetAsync(agg, 0, (size_t)GN * 512 * sizeof(float), stream);
    edge_aggregate<<<(GE + 3) / 4, 256, 0, stream>>>(src, dst, hpre, aw, denom, agg, aw);

    // ---- pool + head
    hipMemsetAsync(pooled, 0, GB * 512 * sizeof(unsigned), stream);
    post2_pool<<<2048, 256, 0, stream>>>(agg, b2, gid, pooled);
    head_mlp<<<GB, 256, 0, stream>>>(pooled, Wa, ba, Wb, bb, g2, bt2, Wc, bc, probs);
}

// Round 2
// 340.026 us; speedup vs baseline: 2.1998x; 2.1998x over previous
//
#include <hip/hip_runtime.h>
#include <hip/hip_bf16.h>

#define GN 10000
#define GE 160000
#define GH 4
#define GD 128
#define GHD 512
#define GB 64
#define GC 2
#define GFF 768
#define SLOPE 0.2f

__device__ __forceinline__ float leaky(float x) { return x >= 0.0f ? x : SLOPE * x; }

// ---------------- GEMM: [rows,128] x [128,512] -> [rows,512], rows % 16 == 0
__global__ __launch_bounds__(256) void gemm_128x512(const float* __restrict__ X,
                                                    const float* __restrict__ W,
                                                    float* __restrict__ Y) {
    __shared__ float xs[16 * 128];
    const int row0 = blockIdx.x * 16;
    const int t = threadIdx.x;
    const float4* X4 = (const float4*)(X + (size_t)row0 * 128);
    float4* xs4v = (float4*)xs;
#pragma unroll
    for (int i = 0; i < 2; ++i) xs4v[i * 256 + t] = X4[i * 256 + t];
    __syncthreads();
    const int c0 = t, c1 = t + 256;
    float acc0[16], acc1[16];
#pragma unroll
    for (int r = 0; r < 16; ++r) { acc0[r] = 0.f; acc1[r] = 0.f; }
    const float4* xs4 = (const float4*)xs;
    for (int f4 = 0; f4 < 32; ++f4) {
        float w0q[4], w1q[4];
#pragma unroll
        for (int q = 0; q < 4; ++q) {
            w0q[q] = W[(f4 * 4 + q) * 512 + c0];
            w1q[q] = W[(f4 * 4 + q) * 512 + c1];
        }
#pragma unroll
        for (int r = 0; r < 16; ++r) {
            float4 xv = xs4[r * 32 + f4];
            acc0[r] += xv.x * w0q[0] + xv.y * w0q[1] + xv.z * w0q[2] + xv.w * w0q[3];
            acc1[r] += xv.x * w1q[0] + xv.y * w1q[1] + xv.z * w1q[2] + xv.w * w1q[3];
        }
    }
#pragma unroll
    for (int r = 0; r < 16; ++r) {
        Y[(size_t)(row0 + r) * 512 + c0] = acc0[r];
        Y[(size_t)(row0 + r) * 512 + c1] = acc1[r];
    }
}

// ---------------- per-node attention logits
__global__ __launch_bounds__(256) void node_logits(const float* __restrict__ hpre,
                                                   const float* __restrict__ al,
                                                   const float* __restrict__ ar,
                                                   float* __restrict__ el,
                                                   float* __restrict__ er) {
    const int wid = threadIdx.x >> 6;
    const int lane = threadIdx.x & 63;
    const int n = blockIdx.x * 4 + wid;
    if (n >= GN) return;
    const float* hp = hpre + (size_t)n * 512;
#pragma unroll
    for (int h = 0; h < 4; ++h) {
        float h0 = hp[h * 128 + lane], h1 = hp[h * 128 + 64 + lane];
        float a = h0 * al[h * 128 + lane] + h1 * al[h * 128 + 64 + lane];
        float b = h0 * ar[h * 128 + lane] + h1 * ar[h * 128 + 64 + lane];
#pragma unroll
        for (int off = 32; off; off >>= 1) {
            a += __shfl_xor(a, off);
            b += __shfl_xor(b, off);
        }
        if (lane == 0) { el[n * 4 + h] = a; er[n * 4 + h] = b; }
    }
}

// ---------------- CSR build: histogram, exclusive scan, scatter
__global__ __launch_bounds__(256) void hist_kernel(const int* __restrict__ dst, int* __restrict__ deg) {
    const int e = blockIdx.x * blockDim.x + threadIdx.x;
    if (e < GE) atomicAdd(&deg[dst[e]], 1);
}

__global__ __launch_bounds__(1024) void exscan_kernel(const int* __restrict__ deg,
                                                      int* __restrict__ rs,      // N+1
                                                      int* __restrict__ cursor) { // N
    __shared__ int part[1024];
    const int t = threadIdx.x;
    const int CH = 10;  // 1024*10 >= GN
    const int base = t * CH;
    int local[CH];
    int s = 0;
#pragma unroll
    for (int i = 0; i < CH; ++i) {
        int idx = base + i;
        int v = (idx < GN) ? deg[idx] : 0;
        local[i] = s;
        s += v;
    }
    part[t] = s;
    __syncthreads();
    for (int off = 1; off < 1024; off <<= 1) {
        int v = part[t];
        int u = (t >= off) ? part[t - off] : 0;
        __syncthreads();
        part[t] = v + u;
        __syncthreads();
    }
    const int chunk_base = (t == 0) ? 0 : part[t - 1];
#pragma unroll
    for (int i = 0; i < CH; ++i) {
        int idx = base + i;
        if (idx < GN) {
            int v = chunk_base + local[i];
            rs[idx] = v;
            cursor[idx] = v;
        }
    }
    if (t == 1023) rs[GN] = part[1023];
}

__global__ __launch_bounds__(256) void scatter_kernel(const int* __restrict__ dst,
                                                      int* __restrict__ cursor,
                                                      int* __restrict__ eidx) {
    const int e = blockIdx.x * blockDim.x + threadIdx.x;
    if (e < GE) {
        int p = atomicAdd(&cursor[dst[e]], 1);
        eidx[p] = e;
    }
}

// ---------------- per-edge: ex[e,h] = exp(leaky(el[src]+er[dst]))   (no atomics)
__global__ __launch_bounds__(256) void edge_exp(const int* __restrict__ src,
                                                const int* __restrict__ dst,
                                                const float* __restrict__ el,
                                                const float* __restrict__ er,
                                                float* __restrict__ ex) {
    const int e = blockIdx.x * blockDim.x + threadIdx.x;
    if (e >= GE) return;
    const float4 l = ((const float4*)el)[src[e]];
    const float4 r = ((const float4*)er)[dst[e]];
    float4 o;
    o.x = __expf(leaky(l.x + r.x));
    o.y = __expf(leaky(l.y + r.y));
    o.z = __expf(leaky(l.z + r.z));
    o.w = __expf(leaky(l.w + r.w));
    ((float4*)ex)[e] = o;
}

// ---------------- layer-1 gather: softmax-denom + aggregate + bias + head-mean + LN + leaky
__global__ __launch_bounds__(256) void gather_l1(const int* __restrict__ rs,
                                                 const int* __restrict__ eidx,
                                                 const int* __restrict__ src,
                                                 const float* __restrict__ hpre,
                                                 const float* __restrict__ ex,
                                                 const float* __restrict__ b1,
                                                 const float* __restrict__ ln_g,
                                                 const float* __restrict__ ln_b,
                                                 float* __restrict__ h1) {
    const int wid = threadIdx.x >> 6, lane = threadIdx.x & 63;
    const int n = blockIdx.x * 4 + wid;
    if (n >= GN) return;
    const int beg = rs[n], end = rs[n + 1];
    const float4* ex4 = (const float4*)ex;
    float4 d4 = {0.f, 0.f, 0.f, 0.f};
    for (int i = beg; i < end; ++i) {
        float4 v = ex4[eidx[i]];
        d4.x += v.x; d4.y += v.y; d4.z += v.z; d4.w += v.w;
    }
    const float i0 = 1.f / fmaxf(d4.x, 1e-9f), i1 = 1.f / fmaxf(d4.y, 1e-9f);
    const float i2 = 1.f / fmaxf(d4.z, 1e-9f), i3 = 1.f / fmaxf(d4.w, 1e-9f);
    float acc[8] = {0.f, 0.f, 0.f, 0.f, 0.f, 0.f, 0.f, 0.f};
    for (int i = beg; i < end; ++i) {
        const int e = eidx[i];
        const int s = src[e];
        const float4 v = ex4[e];
        const float a[4] = {v.x * i0, v.y * i1, v.z * i2, v.w * i3};
        const float* hs = hpre + (size_t)s * 512 + lane;
#pragma unroll
        for (int j = 0; j < 8; ++j) acc[j] += a[j >> 1] * hs[j * 64];
    }
    // + bias, mean over heads (features f = lane + 64j, head = j>>1, d = lane + 64*(j&1))
    float m0 = 0.f, m1 = 0.f;
#pragma unroll
    for (int j = 0; j < 8; ++j) {
        float v = acc[j] + b1[lane + 64 * j];
        if (j & 1) m1 += v; else m0 += v;
    }
    m0 *= 0.25f; m1 *= 0.25f;
    float s = m0 + m1;
#pragma unroll
    for (int off = 32; off; off >>= 1) s += __shfl_xor(s, off);
    const float mean = s * (1.0f / 128.0f);
    const float dd0 = m0 - mean, dd1 = m1 - mean;
    float q = dd0 * dd0 + dd1 * dd1;
#pragma unroll
    for (int off = 32; off; off >>= 1) q += __shfl_xor(q, off);
    const float inv = rsqrtf(q * (1.0f / 128.0f) + 1e-5f);
    h1[(size_t)n * 128 + lane]      = leaky(dd0 * inv * ln_g[lane] + ln_b[lane]);
    h1[(size_t)n * 128 + 64 + lane] = leaky(dd1 * inv * ln_g[64 + lane] + ln_b[64 + lane]);
}

// ---------------- layer-2 gather: denom + aggregate + aw write + bias + leaky + pool atomicMax
__global__ __launch_bounds__(256) void gather_l2(const int* __restrict__ rs,
                                                 const int* __restrict__ eidx,
                                                 const int* __restrict__ src,
                                                 const float* __restrict__ hpre,
                                                 const float* __restrict__ ex,
                                                 const float* __restrict__ b2,
                                                 const int* __restrict__ gid,
                                                 unsigned* __restrict__ pooled,
                                                 float* __restrict__ aw) {
    const int wid = threadIdx.x >> 6, lane = threadIdx.x & 63;
    const int n = blockIdx.x * 4 + wid;
    if (n >= GN) return;
    const int beg = rs[n], end = rs[n + 1];
    const float4* ex4 = (const float4*)ex;
    float4 d4 = {0.f, 0.f, 0.f, 0.f};
    for (int i = beg; i < end; ++i) {
        float4 v = ex4[eidx[i]];
        d4.x += v.x; d4.y += v.y; d4.z += v.z; d4.w += v.w;
    }
    const float i0 = 1.f / fmaxf(d4.x, 1e-9f), i1 = 1.f / fmaxf(d4.y, 1e-9f);
    const float i2 = 1.f / fmaxf(d4.z, 1e-9f), i3 = 1.f / fmaxf(d4.w, 1e-9f);
    float acc[8] = {0.f, 0.f, 0.f, 0.f, 0.f, 0.f, 0.f, 0.f};
    for (int i = beg; i < end; ++i) {
        const int e = eidx[i];
        const int s = src[e];
        const float4 v = ex4[e];
        const float a[4] = {v.x * i0, v.y * i1, v.z * i2, v.w * i3};
        if (lane == 0) {
            float4 o = {a[0], a[1], a[2], a[3]};
            ((float4*)aw)[e] = o;
        }
        const float* hs = hpre + (size_t)s * 512 + lane;
#pragma unroll
        for (int j = 0; j < 8; ++j) acc[j] += a[j >> 1] * hs[j * 64];
    }
    const int g = gid[n];
    unsigned* pg = pooled + (size_t)g * 512;
#pragma unroll
    for (int j = 0; j < 8; ++j) {
        const int f = lane + 64 * j;
        const float v = leaky(acc[j] + b2[f]);
        unsigned bits = __float_as_uint(v);
        unsigned key = (bits & 0x80000000u) ? ~bits : (bits | 0x80000000u);
        atomicMax(&pg[f], key);
    }
}

__device__ __forceinline__ float blk_sum(float v, float* red) {
#pragma unroll
    for (int off = 32; off; off >>= 1) v += __shfl_xor(v, off);
    const int wid = threadIdx.x >> 6, lane = threadIdx.x & 63;
    __syncthreads();
    if (lane == 0) red[wid] = v;
    __syncthreads();
    return red[0] + red[1] + red[2] + red[3];
}

// ---------------- head MLP: one block per graph
__global__ __launch_bounds__(256) void head_mlp(const unsigned* __restrict__ pooled,
                                                const float* __restrict__ Wa, const float* __restrict__ ba,
                                                const float* __restrict__ Wb, const float* __restrict__ bb,
                                                const float* __restrict__ g2, const float* __restrict__ bt2,
                                                const float* __restrict__ Wc, const float* __restrict__ bc,
                                                float* __restrict__ probs) {
    __shared__ float p[512];
    __shared__ float z1[128];
    __shared__ float z2[768];
    __shared__ float red[4];
    const int g = blockIdx.x, t = threadIdx.x;
    for (int i = t; i < 512; i += 256) {
        unsigned key = pooled[(size_t)g * 512 + i];
        unsigned bits = (key & 0x80000000u) ? (key ^ 0x80000000u) : ~key;
        p[i] = __uint_as_float(bits);
    }
    __syncthreads();
    for (int j = t; j < 128; j += 256) {
        float acc = ba[j];
        for (int c = 0; c < 512; ++c) acc += p[c] * Wa[c * 128 + j];
        z1[j] = acc;
    }
    __syncthreads();
    for (int k = t; k < 768; k += 256) {
        float acc = bb[k];
        for (int j = 0; j < 128; ++j) acc += z1[j] * Wb[j * 768 + k];
        z2[k] = acc;
    }
    __syncthreads();
    float s = 0.f;
    for (int k = t; k < 768; k += 256) s += z2[k];
    const float mean = blk_sum(s, red) * (1.0f / 768.0f);
    float q = 0.f;
    for (int k = t; k < 768; k += 256) { float d = z2[k] - mean; q += d * d; }
    const float inv = rsqrtf(blk_sum(q, red) * (1.0f / 768.0f) + 1e-5f);
    __syncthreads();
    for (int k = t; k < 768; k += 256)
        z2[k] = leaky((z2[k] - mean) * inv * g2[k] + bt2[k]);
    __syncthreads();
    float a0 = 0.f, a1 = 0.f;
    for (int k = t; k < 768; k += 256) { a0 += z2[k] * Wc[k * 2]; a1 += z2[k] * Wc[k * 2 + 1]; }
    a0 = blk_sum(a0, red);
    a1 = blk_sum(a1, red);
    if (t == 0) {
        a0 += bc[0]; a1 += bc[1];
        const float m = fmaxf(a0, a1);
        const float e0 = __expf(a0 - m), e1 = __expf(a1 - m);
        const float den = e0 + e1;
        probs[g * 2 + 0] = e0 / den;
        probs[g * 2 + 1] = e1 / den;
    }
}

extern "C" void kernel_launch(void* const* d_in, const int* in_sizes, int n_in,
                              void* d_out, int out_size, void* d_ws, size_t ws_size,
                              hipStream_t stream) {
    const float* x   = (const float*)d_in[0];
    const int* src   = (const int*)d_in[1];
    const int* dst   = (const int*)d_in[2];
    const int* gid   = (const int*)d_in[3];
    const float* W1  = (const float*)d_in[4];
    const float* al1 = (const float*)d_in[5];
    const float* ar1 = (const float*)d_in[6];
    const float* b1  = (const float*)d_in[7];
    const float* lng = (const float*)d_in[8];
    const float* lnb = (const float*)d_in[9];
    const float* W2  = (const float*)d_in[10];
    const float* al2 = (const float*)d_in[11];
    const float* ar2 = (const float*)d_in[12];
    const float* b2  = (const float*)d_in[13];
    const float* Wa  = (const float*)d_in[14];
    const float* ba  = (const float*)d_in[15];
    const float* Wb  = (const float*)d_in[16];
    const float* bb  = (const float*)d_in[17];
    const float* g2  = (const float*)d_in[18];
    const float* bt2 = (const float*)d_in[19];
    const float* Wc  = (const float*)d_in[20];
    const float* bc  = (const float*)d_in[21];

    float* ws = (float*)d_ws;
    float* hpre  = ws;                                 // N*512
    float* h1    = hpre + (size_t)GN * 512;            // N*128
    float* el    = h1 + (size_t)GN * 128;              // N*4
    float* er    = el + GN * 4;                        // N*4
    float* ex1   = er + GN * 4;                        // E*4
    int* deg     = (int*)(ex1 + (size_t)GE * 4);       // N
    int* rs      = deg + GN;                           // N+1
    int* cursor  = rs + GN + 1;                        // N
    int* eidx    = cursor + GN;                        // E
    unsigned* pooled = (unsigned*)(eidx + GE);         // B*512

    float* probs = (float*)d_out;
    float* aw = probs + GB * GC;  // E*4 floats

    // ---- CSR by dst (shared by both layers)
    hipMemsetAsync(deg, 0, GN * sizeof(int), stream);
    hist_kernel<<<(GE + 255) / 256, 256, 0, stream>>>(dst, deg);
    exscan_kernel<<<1, 1024, 0, stream>>>(deg, rs, cursor);
    scatter_kernel<<<(GE + 255) / 256, 256, 0, stream>>>(dst, cursor, eidx);

    // ---- layer 1
    gemm_128x512<<<GN / 16, 256, 0, stream>>>(x, W1, hpre);
    node_logits<<<(GN + 3) / 4, 256, 0, stream>>>(hpre, al1, ar1, el, er);
    edge_exp<<<(GE + 255) / 256, 256, 0, stream>>>(src, dst, el, er, ex1);
    gather_l1<<<(GN + 3) / 4, 256, 0, stream>>>(rs, eidx, src, hpre, ex1, b1, lng, lnb, h1);

    // ---- layer 2
    gemm_128x512<<<GN / 16, 256, 0, stream>>>(h1, W2, hpre);
    node_logits<<<(GN + 3) / 4, 256, 0, stream>>>(hpre, al2, ar2, el, er);
    edge_exp<<<(GE + 255) / 256, 256, 0, stream>>>(src, dst, el, er, ex1);
    hipMemsetAsync(pooled, 0, GB * 512 * sizeof(unsigned), stream);
    gather_l2<<<(GN + 3) / 4, 256, 0, stream>>>(rs, eidx, src, hpre, ex1, b2, gid, pooled, aw);

    // ---- head
    head_mlp<<<GB, 256, 0, stream>>>(pooled, Wa, ba, Wb, bb, g2, bt2, Wc, bc, probs);
}